// Round 12
// baseline (1238.575 us; speedup 1.0000x reference)
//
#include <hip/hip_runtime.h>

#define AA 60
#define HH 96
#define WW 96
#define DD 96
#define HWP (HH * WW)   // 9216
#define ADP (AA * DD)   // 5760
#define NITER 10
#define MATEL (60 * 96 * 9216)   // 53,084,160 elements per system matrix

typedef unsigned short ushort8 __attribute__((ext_vector_type(8)));
typedef float float4v __attribute__((ext_vector_type(4)));

__device__ inline float b2f(unsigned short u) {
    return __uint_as_float(((unsigned)u) << 16);
}
__device__ inline unsigned short f2b(float f) {
    unsigned u = __float_as_uint(f);
    u += 0x7FFFu + ((u >> 16) & 1u);
    return (unsigned short)(u >> 16);
}

// xd[3][5760]: ch0=dual, ch1=evalop1, ch2=g ; xp[6][9216]: ch0..4=p2d, ch5=evalop2
__global__ __launch_bounds__(256) void init_kernel(const float* __restrict__ dual,
                            const float* __restrict__ g,
                            const float* __restrict__ primal,
                            float* __restrict__ xd, float* __restrict__ xp,
                            float* __restrict__ imgf, float* __restrict__ xp5) {
    int i = blockIdx.x * 256 + threadIdx.x;
    if (i < ADP) { xd[i] = dual[i]; xd[2 * ADP + i] = g[i]; }
    if (i < 5 * HWP) xp[i] = primal[i];
    if (i < HWP) {
        imgf[(i % WW) * HH + i / WW] = primal[HWP + i];
        xp5[i] = 0.f;
    }
}

// ---- iter 0: einsum1 from f32 source + bf16 writeback (fused cvt) ----
__global__ __launch_bounds__(256) void einsum1_cvt(const float* __restrict__ norm,
                               const float* __restrict__ imgf,
                               float* __restrict__ out,
                               unsigned short* __restrict__ normb) {
    int rp   = blockIdx.x * 4 + (threadIdx.x >> 6);   // 0..2879
    int lane = threadIdx.x & 63;
    const float* r0 = norm + (size_t)(2 * rp) * HWP;
    const float* r1 = r0 + HWP;
    unsigned short* w0 = normb + (size_t)(2 * rp) * HWP;
    unsigned short* w1 = w0 + HWP;
    float s0 = 0.f, s1 = 0.f;
    for (int k = 0; k < HWP / 512; ++k) {   // 18 iters
        int n = 8 * lane + 512 * k;
        float4 a0 = *reinterpret_cast<const float4*>(r0 + n);
        float4 a1 = *reinterpret_cast<const float4*>(r0 + n + 4);
        float4 b0 = *reinterpret_cast<const float4*>(r1 + n);
        float4 b1 = *reinterpret_cast<const float4*>(r1 + n + 4);
        float4 i0 = *reinterpret_cast<const float4*>(imgf + n);
        float4 i1 = *reinterpret_cast<const float4*>(imgf + n + 4);
        ushort8 oa, ob;
        oa[0] = f2b(a0.x); oa[1] = f2b(a0.y); oa[2] = f2b(a0.z); oa[3] = f2b(a0.w);
        oa[4] = f2b(a1.x); oa[5] = f2b(a1.y); oa[6] = f2b(a1.z); oa[7] = f2b(a1.w);
        ob[0] = f2b(b0.x); ob[1] = f2b(b0.y); ob[2] = f2b(b0.z); ob[3] = f2b(b0.w);
        ob[4] = f2b(b1.x); ob[5] = f2b(b1.y); ob[6] = f2b(b1.z); ob[7] = f2b(b1.w);
        *reinterpret_cast<ushort8*>(w0 + n) = oa;
        *reinterpret_cast<ushort8*>(w1 + n) = ob;
        s0 += a0.x * i0.x + a0.y * i0.y + a0.z * i0.z + a0.w * i0.w
            + a1.x * i1.x + a1.y * i1.y + a1.z * i1.z + a1.w * i1.w;
        s1 += b0.x * i0.x + b0.y * i0.y + b0.z * i0.z + b0.w * i0.w
            + b1.x * i1.x + b1.y * i1.y + b1.z * i1.z + b1.w * i1.w;
    }
#pragma unroll
    for (int off = 32; off > 0; off >>= 1) {
        s0 += __shfl_down(s0, off);
        s1 += __shfl_down(s1, off);
    }
    if (lane == 0) { out[2 * rp] = s0; out[2 * rp + 1] = s1; }
}

// ---- iters 1-9: einsum1 from bf16 (L3-resident); one wave per row-pair ----
__global__ __launch_bounds__(256) void einsum1_kernel(const unsigned short* __restrict__ norm,
                               const float* __restrict__ imgf,
                               float* __restrict__ out) {
    int rp   = blockIdx.x * 4 + (threadIdx.x >> 6);   // 0..2879
    int lane = threadIdx.x & 63;
    const unsigned short* r0 = norm + (size_t)(2 * rp) * HWP;
    const unsigned short* r1 = r0 + HWP;
    float s0 = 0.f, s1 = 0.f;
    for (int k = 0; k < HWP / 512; ++k) {   // 18 iters
        int n = 8 * lane + 512 * k;
        ushort8 a8 = *reinterpret_cast<const ushort8*>(r0 + n);
        ushort8 b8 = *reinterpret_cast<const ushort8*>(r1 + n);
        float4 i0 = *reinterpret_cast<const float4*>(imgf + n);
        float4 i1 = *reinterpret_cast<const float4*>(imgf + n + 4);
        s0 += b2f(a8[0]) * i0.x + b2f(a8[1]) * i0.y + b2f(a8[2]) * i0.z + b2f(a8[3]) * i0.w
            + b2f(a8[4]) * i1.x + b2f(a8[5]) * i1.y + b2f(a8[6]) * i1.z + b2f(a8[7]) * i1.w;
        s1 += b2f(b8[0]) * i0.x + b2f(b8[1]) * i0.y + b2f(b8[2]) * i0.z + b2f(b8[3]) * i0.w
            + b2f(b8[4]) * i1.x + b2f(b8[5]) * i1.y + b2f(b8[6]) * i1.z + b2f(b8[7]) * i1.w;
    }
#pragma unroll
    for (int off = 32; off > 0; off >>= 1) {
        s0 += __shfl_down(s0, off);
        s1 += __shfl_down(s1, off);
    }
    if (lane == 0) { out[2 * rp] = s0; out[2 * rp + 1] = s1; }
}

// ---- iter 0: einsum2 from f32 source + bf16 writeback (fused cvt) ----
__global__ __launch_bounds__(256) void einsum2_cvt(const float* __restrict__ sysm,
                               const float* __restrict__ xd,
                               float* __restrict__ xp5,
                               unsigned short* __restrict__ sysmb) {
    __shared__ float sd[4 * DD];
    int t  = threadIdx.x;
    int a0 = (blockIdx.x % 15) * 4;
    int v  = (blockIdx.x / 15) * 256 + t;
    for (int j = t; j < 4 * DD; j += 256) sd[j] = xd[a0 * DD + j];
    __syncthreads();
    float s = 0.f;
    for (int ai = 0; ai < 4; ++ai) {
        size_t off = ((size_t)(a0 + ai) * HWP + v) * DD;
        const float* row = sysm + off;
        unsigned short* wr = sysmb + off;
        const float* dl = sd + ai * DD;
#pragma unroll
        for (int jj = 0; jj < DD / 8; ++jj) {
            float4 x = *reinterpret_cast<const float4*>(row + 8 * jj);
            float4 y = *reinterpret_cast<const float4*>(row + 8 * jj + 4);
            ushort8 o;
            o[0] = f2b(x.x); o[1] = f2b(x.y); o[2] = f2b(x.z); o[3] = f2b(x.w);
            o[4] = f2b(y.x); o[5] = f2b(y.y); o[6] = f2b(y.z); o[7] = f2b(y.w);
            *reinterpret_cast<ushort8*>(wr + 8 * jj) = o;
            s += x.x * dl[8 * jj]     + x.y * dl[8 * jj + 1]
               + x.z * dl[8 * jj + 2] + x.w * dl[8 * jj + 3]
               + y.x * dl[8 * jj + 4] + y.y * dl[8 * jj + 5]
               + y.z * dl[8 * jj + 6] + y.w * dl[8 * jj + 7];
        }
    }
    atomicAdd(xp5 + (v % HH) * WW + (v / HH), s);
}

// ---- iters 1-9: einsum2 from bf16 ----
__global__ __launch_bounds__(256) void einsum2_kernel(const unsigned short* __restrict__ sysm,
                               const float* __restrict__ xd,
                               float* __restrict__ xp5) {
    __shared__ float sd[4 * DD];
    int t  = threadIdx.x;
    int a0 = (blockIdx.x % 15) * 4;
    int v  = (blockIdx.x / 15) * 256 + t;
    for (int j = t; j < 4 * DD; j += 256) sd[j] = xd[a0 * DD + j];
    __syncthreads();
    float s = 0.f;
    for (int ai = 0; ai < 4; ++ai) {
        const unsigned short* row = sysm + ((size_t)(a0 + ai) * HWP + v) * DD;
        const float* dl = sd + ai * DD;
#pragma unroll
        for (int jj = 0; jj < DD / 8; ++jj) {
            ushort8 m8 = *reinterpret_cast<const ushort8*>(row + 8 * jj);
            s += b2f(m8[0]) * dl[8 * jj]     + b2f(m8[1]) * dl[8 * jj + 1]
               + b2f(m8[2]) * dl[8 * jj + 2] + b2f(m8[3]) * dl[8 * jj + 3]
               + b2f(m8[4]) * dl[8 * jj + 4] + b2f(m8[5]) * dl[8 * jj + 5]
               + b2f(m8[6]) * dl[8 * jj + 6] + b2f(m8[7]) * dl[8 * jj + 7];
        }
    }
    atomicAdd(xp5 + (v % HH) * WW + (v / HH), s);
}

// 3x3 conv pad=1, PReLU. Grid: (hw/64, Cout/NOUT), block 64.
template <int CIN, int NOUT>
__global__ __launch_bounds__(64) void conv_mid(
        const float* __restrict__ in,
        const float* __restrict__ wgt,   // [Cout][CIN][3][3]
        const float* __restrict__ bias,
        const float* __restrict__ alpha,
        float* __restrict__ out,
        int Hc, int Wc) {
    int hw  = Hc * Wc;
    int pix = blockIdx.x * 64 + threadIdx.x;
    int y = pix / Wc, x = pix % Wc;
    int oc0 = blockIdx.y * NOUT;
    const float* wb = wgt + (size_t)oc0 * CIN * 9;
    float a = alpha[0];
    float acc[NOUT];
#pragma unroll
    for (int o = 0; o < NOUT; ++o) acc[o] = bias[oc0 + o];
    for (int ci = 0; ci < CIN; ++ci) {
        const float* ip = in + ci * hw;
#pragma unroll
        for (int ky = 0; ky < 3; ++ky) {
            int yy = y + ky - 1;
            bool yok = (unsigned)yy < (unsigned)Hc;
#pragma unroll
            for (int kx = 0; kx < 3; ++kx) {
                int xx = x + kx - 1;
                bool vok = yok && ((unsigned)xx < (unsigned)Wc);
                float v = ip[vok ? yy * Wc + xx : 0];
                v = vok ? v : 0.f;
#pragma unroll
                for (int o = 0; o < NOUT; ++o)
                    acc[o] += wb[(o * CIN + ci) * 9 + ky * 3 + kx] * v;
            }
        }
    }
#pragma unroll
    for (int o = 0; o < NOUT; ++o) {
        float r = acc[o];
        r = (r >= 0.f) ? r : a * r;
        out[(oc0 + o) * hw + pix] = r;
    }
}

// dual conv3 (32->1) + residual into xd ch0, split over ci-chunks of 4 (atomicAdd)
__global__ __launch_bounds__(64) void conv3d_last(const float* __restrict__ in,
        const float* __restrict__ wgt,   // [32][9]
        const float* __restrict__ bias,  // [1]
        float* __restrict__ xd) {
    int pix = blockIdx.x * 64 + threadIdx.x;   // 0..5759
    int y = pix / DD, x = pix % DD;
    int c0 = blockIdx.y * 4;
    float r = (blockIdx.y == 0) ? bias[0] : 0.f;
    for (int ci = c0; ci < c0 + 4; ++ci) {
        const float* ip = in + ci * ADP;
#pragma unroll
        for (int ky = 0; ky < 3; ++ky) {
            int yy = y + ky - 1;
            bool yok = (unsigned)yy < (unsigned)AA;
#pragma unroll
            for (int kx = 0; kx < 3; ++kx) {
                int xx = x + kx - 1;
                bool vok = yok && ((unsigned)xx < (unsigned)DD);
                float v = ip[vok ? yy * DD + xx : 0];
                v = vok ? v : 0.f;
                r += wgt[ci * 9 + ky * 3 + kx] * v;
            }
        }
    }
    atomicAdd(xd + pix, r);
}

// primal conv3 (32->5) + residual into xp; fused: imgf for next iter (ch1),
// xp5 zero (ch2 block), final output write (ch0 block, last iter)
__global__ __launch_bounds__(64) void conv3p_last(const float* __restrict__ in,
        const float* __restrict__ wgt,   // [5][32][9]
        const float* __restrict__ bias,  // [5]
        float* __restrict__ xp, float* __restrict__ imgf,
        float* __restrict__ xp5, float* __restrict__ dout, int fin) {
    int pix = blockIdx.x * 64 + threadIdx.x;   // 0..9215
    int y = pix / WW, x = pix % WW;
    int oc = blockIdx.y;                       // 0..4
    const float* wb = wgt + (size_t)oc * 32 * 9;
    float r = bias[oc];
    for (int ci = 0; ci < 32; ++ci) {
        const float* ip = in + ci * HWP;
#pragma unroll
        for (int ky = 0; ky < 3; ++ky) {
            int yy = y + ky - 1;
            bool yok = (unsigned)yy < (unsigned)HH;
#pragma unroll
            for (int kx = 0; kx < 3; ++kx) {
                int xx = x + kx - 1;
                bool vok = yok && ((unsigned)xx < (unsigned)WW);
                float v = ip[vok ? yy * WW + xx : 0];
                v = vok ? v : 0.f;
                r += wb[ci * 9 + ky * 3 + kx] * v;
            }
        }
    }
    float nv = xp[oc * HWP + pix] + r;
    xp[oc * HWP + pix] = nv;
    if (oc == 1) imgf[x * HH + y] = nv;    // fortran flatten for next einsum1
    if (oc == 2) xp5[pix] = 0.f;           // clear evalop2 accumulator
    if (fin && oc == 0) dout[pix] = nv;    // final output
}

extern "C" void kernel_launch(void* const* d_in, const int* in_sizes, int n_in,
                              void* d_out, int out_size, void* d_ws, size_t ws_size,
                              hipStream_t stream) {
    const float* dual   = (const float*)d_in[0];
    const float* primal = (const float*)d_in[1];
    const float* g      = (const float*)d_in[2];
    const float* sysm   = (const float*)d_in[3];
    const float* norm   = (const float*)d_in[4];
    const float* dw1 = (const float*)d_in[5];
    const float* db1 = (const float*)d_in[6];
    const float* da1 = (const float*)d_in[7];
    const float* dw2 = (const float*)d_in[8];
    const float* db2 = (const float*)d_in[9];
    const float* da2 = (const float*)d_in[10];
    const float* dw3 = (const float*)d_in[11];
    const float* db3 = (const float*)d_in[12];
    const float* pw1 = (const float*)d_in[13];
    const float* pb1 = (const float*)d_in[14];
    const float* pa1 = (const float*)d_in[15];
    const float* pw2 = (const float*)d_in[16];
    const float* pb2 = (const float*)d_in[17];
    const float* pa2 = (const float*)d_in[18];
    const float* pw3 = (const float*)d_in[19];
    const float* pb3 = (const float*)d_in[20];

    unsigned short* normb = (unsigned short*)d_ws;     // MATEL bf16 [row][n]
    unsigned short* sysmb = normb + MATEL;             // MATEL bf16 [a][v][n]
    float* xd   = (float*)(sysmb + MATEL);             // 3*5760
    float* xp   = xd + 3 * ADP;                        // 6*9216
    float* imgf = xp + 6 * HWP;                        // 9216
    float* h1   = imgf + HWP;                          // 32*5760
    float* h2   = h1 + 32 * ADP;                       // 32*5760
    float* g1   = h2 + 32 * ADP;                       // 32*9216
    float* g2   = g1 + 32 * HWP;                       // 32*9216

    init_kernel<<<(5 * HWP + 255) / 256, 256, 0, stream>>>(dual, g, primal, xd, xp, imgf, xp + 5 * HWP);

    for (int k = 0; k < NITER; ++k) {
        // ---- dual half ----
        if (k == 0)
            einsum1_cvt<<<ADP / 8, 256, 0, stream>>>(norm, imgf, xd + ADP, normb);
        else
            einsum1_kernel<<<ADP / 8, 256, 0, stream>>>(normb, imgf, xd + ADP);
        conv_mid<3, 2><<<dim3(ADP / 64, 16), 64, 0, stream>>>(
            xd, dw1 + k * 32 * 3 * 9, db1 + k * 32, da1 + k, h1, AA, DD);
        conv_mid<32, 2><<<dim3(ADP / 64, 16), 64, 0, stream>>>(
            h1, dw2 + k * 32 * 32 * 9, db2 + k * 32, da2 + k, h2, AA, DD);
        conv3d_last<<<dim3(ADP / 64, 8), 64, 0, stream>>>(
            h2, dw3 + k * 32 * 9, db3 + k, xd);
        // ---- primal half ----
        if (k == 0)
            einsum2_cvt<<<15 * 36, 256, 0, stream>>>(sysm, xd, xp + 5 * HWP, sysmb);
        else
            einsum2_kernel<<<15 * 36, 256, 0, stream>>>(sysmb, xd, xp + 5 * HWP);
        conv_mid<6, 2><<<dim3(HWP / 64, 16), 64, 0, stream>>>(
            xp, pw1 + k * 32 * 6 * 9, pb1 + k * 32, pa1 + k, g1, HH, WW);
        conv_mid<32, 2><<<dim3(HWP / 64, 16), 64, 0, stream>>>(
            g1, pw2 + k * 32 * 32 * 9, pb2 + k * 32, pa2 + k, g2, HH, WW);
        conv3p_last<<<dim3(HWP / 64, 5), 64, 0, stream>>>(
            g2, pw3 + k * 5 * 32 * 9, pb3 + k * 5, xp, imgf, xp + 5 * HWP,
            (float*)d_out, k == NITER - 1 ? 1 : 0);
    }
}

// Round 13
// 1181.153 us; speedup vs baseline: 1.0486x; 1.0486x over previous
//
#include <hip/hip_runtime.h>

#define AA 60
#define HH 96
#define WW 96
#define DD 96
#define HWP (HH * WW)   // 9216
#define ADP (AA * DD)   // 5760
#define NITER 10
#define MATEL (60 * 96 * 9216)   // 53,084,160 elements per system matrix

typedef unsigned short ushort8 __attribute__((ext_vector_type(8)));
typedef float float4v __attribute__((ext_vector_type(4)));

__device__ inline float b2f(unsigned short u) {
    return __uint_as_float(((unsigned)u) << 16);
}
__device__ inline unsigned short f2b(float f) {
    unsigned u = __float_as_uint(f);
    u += 0x7FFFu + ((u >> 16) & 1u);
    return (unsigned short)(u >> 16);
}

// ---- f32 -> bf16 conversion of both system matrices (once per call) ----
__global__ __launch_bounds__(256) void cvt_kernel(const float* __restrict__ a,
                                                  const float* __restrict__ b,
                                                  ushort8* __restrict__ da,
                                                  ushort8* __restrict__ db, int n8) {
    int stride = gridDim.x * 256;
    for (int i = blockIdx.x * 256 + threadIdx.x; i < 2 * n8; i += stride) {
        const float* src; ushort8* dst; int j;
        if (i < n8) { src = a; dst = da; j = i; }
        else        { src = b; dst = db; j = i - n8; }
        const float4v* s = reinterpret_cast<const float4v*>(src) + 2 * (size_t)j;
        float4v x = __builtin_nontemporal_load(s);
        float4v y = __builtin_nontemporal_load(s + 1);
        ushort8 o;
        o[0] = f2b(x[0]); o[1] = f2b(x[1]); o[2] = f2b(x[2]); o[3] = f2b(x[3]);
        o[4] = f2b(y[0]); o[5] = f2b(y[1]); o[6] = f2b(y[2]); o[7] = f2b(y[3]);
        dst[j] = o;
    }
}

// xd[3][5760]: ch0=dual, ch1=evalop1, ch2=g ; xp[6][9216]: ch0..4=p2d, ch5=evalop2
__global__ __launch_bounds__(256) void init_kernel(const float* __restrict__ dual,
                            const float* __restrict__ g,
                            const float* __restrict__ primal,
                            float* __restrict__ xd, float* __restrict__ xp,
                            float* __restrict__ imgf, float* __restrict__ xp5) {
    int i = blockIdx.x * 256 + threadIdx.x;
    if (i < ADP) { xd[i] = dual[i]; xd[2 * ADP + i] = g[i]; }
    if (i < 5 * HWP) xp[i] = primal[i];
    if (i < HWP) {
        imgf[(i % WW) * HH + i / WW] = primal[HWP + i];
        xp5[i] = 0.f;
    }
}

// prod[row] = dot(norm_bf16[row,:9216], imgf); one wave per ROW-PAIR
__global__ __launch_bounds__(256) void einsum1_kernel(const unsigned short* __restrict__ norm,
                               const float* __restrict__ imgf,
                               float* __restrict__ out) {
    int rp   = blockIdx.x * 4 + (threadIdx.x >> 6);   // 0..2879
    int lane = threadIdx.x & 63;
    const unsigned short* r0 = norm + (size_t)(2 * rp) * HWP;
    const unsigned short* r1 = r0 + HWP;
    float s0 = 0.f, s1 = 0.f;
    for (int k = 0; k < HWP / 512; ++k) {   // 18 iters
        int n = 8 * lane + 512 * k;
        ushort8 a8 = *reinterpret_cast<const ushort8*>(r0 + n);
        ushort8 b8 = *reinterpret_cast<const ushort8*>(r1 + n);
        float4 i0 = *reinterpret_cast<const float4*>(imgf + n);
        float4 i1 = *reinterpret_cast<const float4*>(imgf + n + 4);
        s0 += b2f(a8[0]) * i0.x + b2f(a8[1]) * i0.y + b2f(a8[2]) * i0.z + b2f(a8[3]) * i0.w
            + b2f(a8[4]) * i1.x + b2f(a8[5]) * i1.y + b2f(a8[6]) * i1.z + b2f(a8[7]) * i1.w;
        s1 += b2f(b8[0]) * i0.x + b2f(b8[1]) * i0.y + b2f(b8[2]) * i0.z + b2f(b8[3]) * i0.w
            + b2f(b8[4]) * i1.x + b2f(b8[5]) * i1.y + b2f(b8[6]) * i1.z + b2f(b8[7]) * i1.w;
    }
#pragma unroll
    for (int off = 32; off > 0; off >>= 1) {
        s0 += __shfl_down(s0, off);
        s1 += __shfl_down(s1, off);
    }
    if (lane == 0) { out[2 * rp] = s0; out[2 * rp + 1] = s1; }
}

// vec[v] = sum_{a,n} sysm_bf16[a,v,n]*dual[a,n]; fortran-transposed scatter
__global__ __launch_bounds__(256) void einsum2_kernel(const unsigned short* __restrict__ sysm,
                               const float* __restrict__ xd,
                               float* __restrict__ xp5) {
    __shared__ float sd[4 * DD];
    int t  = threadIdx.x;
    int a0 = (blockIdx.x % 15) * 4;
    int v  = (blockIdx.x / 15) * 256 + t;
    for (int j = t; j < 4 * DD; j += 256) sd[j] = xd[a0 * DD + j];
    __syncthreads();
    float s = 0.f;
    for (int ai = 0; ai < 4; ++ai) {
        const unsigned short* row = sysm + ((size_t)(a0 + ai) * HWP + v) * DD;
        const float* dl = sd + ai * DD;
#pragma unroll
        for (int jj = 0; jj < DD / 8; ++jj) {
            ushort8 m8 = *reinterpret_cast<const ushort8*>(row + 8 * jj);
            s += b2f(m8[0]) * dl[8 * jj]     + b2f(m8[1]) * dl[8 * jj + 1]
               + b2f(m8[2]) * dl[8 * jj + 2] + b2f(m8[3]) * dl[8 * jj + 3]
               + b2f(m8[4]) * dl[8 * jj + 4] + b2f(m8[5]) * dl[8 * jj + 5]
               + b2f(m8[6]) * dl[8 * jj + 6] + b2f(m8[7]) * dl[8 * jj + 7];
        }
    }
    atomicAdd(xp5 + (v % HH) * WW + (v / HH), s);
}

// 3x3 conv pad=1, PReLU, generic (used for CIN=3,6). Grid: (hw/64, Cout/2).
template <int CIN, int NOUT>
__global__ __launch_bounds__(64) void conv_mid(
        const float* __restrict__ in,
        const float* __restrict__ wgt,
        const float* __restrict__ bias,
        const float* __restrict__ alpha,
        float* __restrict__ out,
        int Hc, int Wc) {
    int hw  = Hc * Wc;
    int pix = blockIdx.x * 64 + threadIdx.x;
    int y = pix / Wc, x = pix % Wc;
    int oc0 = blockIdx.y * NOUT;
    const float* wb = wgt + (size_t)oc0 * CIN * 9;
    float a = alpha[0];
    float acc[NOUT];
#pragma unroll
    for (int o = 0; o < NOUT; ++o) acc[o] = bias[oc0 + o];
    for (int ci = 0; ci < CIN; ++ci) {
        const float* ip = in + ci * hw;
#pragma unroll
        for (int ky = 0; ky < 3; ++ky) {
            int yy = y + ky - 1;
            bool yok = (unsigned)yy < (unsigned)Hc;
#pragma unroll
            for (int kx = 0; kx < 3; ++kx) {
                int xx = x + kx - 1;
                bool vok = yok && ((unsigned)xx < (unsigned)Wc);
                float v = ip[vok ? yy * Wc + xx : 0];
                v = vok ? v : 0.f;
#pragma unroll
                for (int o = 0; o < NOUT; ++o)
                    acc[o] += wb[(o * CIN + ci) * 9 + ky * 3 + kx] * v;
            }
        }
    }
#pragma unroll
    for (int o = 0; o < NOUT; ++o) {
        float r = acc[o];
        r = (r >= 0.f) ? r : a * r;
        out[(oc0 + o) * hw + pix] = r;
    }
}

// 32-ci 3x3 conv, 2 adjacent pixels + 2 output channels per thread.
// Window overlap: per ci-row, 1 float2 + 2 scalar loads feed both pixels
// (2x fewer VMEM instructions). Per-pixel tap order preserved (bitwise-identical).
__global__ __launch_bounds__(64) void conv_mid2(
        const float* __restrict__ in,
        const float* __restrict__ wgt,   // [Cout][32][3][3]
        const float* __restrict__ bias,
        const float* __restrict__ alpha,
        float* __restrict__ out,
        int Hc, int Wc) {
    int hw  = Hc * Wc;
    int W2  = Wc >> 1;
    int p2  = blockIdx.x * 64 + threadIdx.x;   // pixel-pair id
    int x2 = p2 % W2, y = p2 / W2;
    int x0 = 2 * x2;
    int oc0 = blockIdx.y * 2;
    const float* wb = wgt + (size_t)oc0 * 32 * 9;
    float a = alpha[0];
    float b0 = bias[oc0], b1 = bias[oc0 + 1];
    float a00 = b0, a01 = b0;   // oc0: px0, px1
    float a10 = b1, a11 = b1;   // oc1: px0, px1
    for (int ci = 0; ci < 32; ++ci) {
        const float* ip = in + ci * hw;
#pragma unroll
        for (int ky = 0; ky < 3; ++ky) {
            int yy = y + ky - 1;
            bool yok = (unsigned)yy < (unsigned)Hc;
            int ro = yok ? yy * Wc : 0;
            bool mok = yok && (x0 > 0);
            bool cok = yok && (x0 + 2 < Wc);
            float2 cc = *reinterpret_cast<const float2*>(ip + ro + x0);
            float cm = ip[mok ? ro + x0 - 1 : 0];
            float c2 = ip[cok ? ro + x0 + 2 : 0];
            float v0 = yok ? cc.x : 0.f;
            float v1 = yok ? cc.y : 0.f;
            cm = mok ? cm : 0.f;
            c2 = cok ? c2 : 0.f;
            float w00 = wb[ci * 9 + ky * 3 + 0];
            float w01 = wb[ci * 9 + ky * 3 + 1];
            float w02 = wb[ci * 9 + ky * 3 + 2];
            float w10 = wb[(32 * 9) + ci * 9 + ky * 3 + 0];
            float w11 = wb[(32 * 9) + ci * 9 + ky * 3 + 1];
            float w12 = wb[(32 * 9) + ci * 9 + ky * 3 + 2];
            // px0 taps: cm, v0, v1 ; px1 taps: v0, v1, c2 (kx order preserved)
            a00 += w00 * cm; a00 += w01 * v0; a00 += w02 * v1;
            a01 += w00 * v0; a01 += w01 * v1; a01 += w02 * c2;
            a10 += w10 * cm; a10 += w11 * v0; a10 += w12 * v1;
            a11 += w10 * v0; a11 += w11 * v1; a11 += w12 * c2;
        }
    }
    a00 = (a00 >= 0.f) ? a00 : a * a00;
    a01 = (a01 >= 0.f) ? a01 : a * a01;
    a10 = (a10 >= 0.f) ? a10 : a * a10;
    a11 = (a11 >= 0.f) ? a11 : a * a11;
    int px = y * Wc + x0;
    float2 o0; o0.x = a00; o0.y = a01;
    float2 o1; o1.x = a10; o1.y = a11;
    *reinterpret_cast<float2*>(out + (size_t)oc0 * hw + px) = o0;
    *reinterpret_cast<float2*>(out + (size_t)(oc0 + 1) * hw + px) = o1;
}

// dual conv3 (32->1) + residual into xd ch0, split over ci-chunks of 4 (atomicAdd)
__global__ __launch_bounds__(64) void conv3d_last(const float* __restrict__ in,
        const float* __restrict__ wgt,   // [32][9]
        const float* __restrict__ bias,  // [1]
        float* __restrict__ xd) {
    int pix = blockIdx.x * 64 + threadIdx.x;   // 0..5759
    int y = pix / DD, x = pix % DD;
    int c0 = blockIdx.y * 4;
    float r = (blockIdx.y == 0) ? bias[0] : 0.f;
    for (int ci = c0; ci < c0 + 4; ++ci) {
        const float* ip = in + ci * ADP;
#pragma unroll
        for (int ky = 0; ky < 3; ++ky) {
            int yy = y + ky - 1;
            bool yok = (unsigned)yy < (unsigned)AA;
#pragma unroll
            for (int kx = 0; kx < 3; ++kx) {
                int xx = x + kx - 1;
                bool vok = yok && ((unsigned)xx < (unsigned)DD);
                float v = ip[vok ? yy * DD + xx : 0];
                v = vok ? v : 0.f;
                r += wgt[ci * 9 + ky * 3 + kx] * v;
            }
        }
    }
    atomicAdd(xd + pix, r);
}

// primal conv3 (32->5) + residual into xp; fused: imgf for next iter (ch1),
// xp5 zero (ch2 block), final output write (ch0 block, last iter)
__global__ __launch_bounds__(64) void conv3p_last(const float* __restrict__ in,
        const float* __restrict__ wgt,   // [5][32][9]
        const float* __restrict__ bias,  // [5]
        float* __restrict__ xp, float* __restrict__ imgf,
        float* __restrict__ xp5, float* __restrict__ dout, int fin) {
    int pix = blockIdx.x * 64 + threadIdx.x;   // 0..9215
    int y = pix / WW, x = pix % WW;
    int oc = blockIdx.y;                       // 0..4
    const float* wb = wgt + (size_t)oc * 32 * 9;
    float r = bias[oc];
    for (int ci = 0; ci < 32; ++ci) {
        const float* ip = in + ci * HWP;
#pragma unroll
        for (int ky = 0; ky < 3; ++ky) {
            int yy = y + ky - 1;
            bool yok = (unsigned)yy < (unsigned)HH;
#pragma unroll
            for (int kx = 0; kx < 3; ++kx) {
                int xx = x + kx - 1;
                bool vok = yok && ((unsigned)xx < (unsigned)WW);
                float v = ip[vok ? yy * WW + xx : 0];
                v = vok ? v : 0.f;
                r += wb[ci * 9 + ky * 3 + kx] * v;
            }
        }
    }
    float nv = xp[oc * HWP + pix] + r;
    xp[oc * HWP + pix] = nv;
    if (oc == 1) imgf[x * HH + y] = nv;    // fortran flatten for next einsum1
    if (oc == 2) xp5[pix] = 0.f;           // clear evalop2 accumulator
    if (fin && oc == 0) dout[pix] = nv;    // final output
}

extern "C" void kernel_launch(void* const* d_in, const int* in_sizes, int n_in,
                              void* d_out, int out_size, void* d_ws, size_t ws_size,
                              hipStream_t stream) {
    const float* dual   = (const float*)d_in[0];
    const float* primal = (const float*)d_in[1];
    const float* g      = (const float*)d_in[2];
    const float* sysm   = (const float*)d_in[3];
    const float* norm   = (const float*)d_in[4];
    const float* dw1 = (const float*)d_in[5];
    const float* db1 = (const float*)d_in[6];
    const float* da1 = (const float*)d_in[7];
    const float* dw2 = (const float*)d_in[8];
    const float* db2 = (const float*)d_in[9];
    const float* da2 = (const float*)d_in[10];
    const float* dw3 = (const float*)d_in[11];
    const float* db3 = (const float*)d_in[12];
    const float* pw1 = (const float*)d_in[13];
    const float* pb1 = (const float*)d_in[14];
    const float* pa1 = (const float*)d_in[15];
    const float* pw2 = (const float*)d_in[16];
    const float* pb2 = (const float*)d_in[17];
    const float* pa2 = (const float*)d_in[18];
    const float* pw3 = (const float*)d_in[19];
    const float* pb3 = (const float*)d_in[20];

    unsigned short* normb = (unsigned short*)d_ws;     // MATEL bf16 [row][n]
    unsigned short* sysmb = normb + MATEL;             // MATEL bf16 [a][v][n]
    float* xd   = (float*)(sysmb + MATEL);             // 3*5760
    float* xp   = xd + 3 * ADP;                        // 6*9216
    float* imgf = xp + 6 * HWP;                        // 9216
    float* h1   = imgf + HWP;                          // 32*5760
    float* h2   = h1 + 32 * ADP;                       // 32*5760
    float* g1   = h2 + 32 * ADP;                       // 32*9216
    float* g2   = g1 + 32 * HWP;                       // 32*9216

    cvt_kernel<<<4096, 256, 0, stream>>>(norm, sysm, (ushort8*)normb, (ushort8*)sysmb, MATEL / 8);
    init_kernel<<<(5 * HWP + 255) / 256, 256, 0, stream>>>(dual, g, primal, xd, xp, imgf, xp + 5 * HWP);

    for (int k = 0; k < NITER; ++k) {
        // ---- dual half ----
        einsum1_kernel<<<ADP / 8, 256, 0, stream>>>(normb, imgf, xd + ADP);
        conv_mid<3, 2><<<dim3(ADP / 64, 16), 64, 0, stream>>>(
            xd, dw1 + k * 32 * 3 * 9, db1 + k * 32, da1 + k, h1, AA, DD);
        conv_mid2<<<dim3(ADP / 128, 16), 64, 0, stream>>>(
            h1, dw2 + k * 32 * 32 * 9, db2 + k * 32, da2 + k, h2, AA, DD);
        conv3d_last<<<dim3(ADP / 64, 8), 64, 0, stream>>>(
            h2, dw3 + k * 32 * 9, db3 + k, xd);
        // ---- primal half ----
        einsum2_kernel<<<15 * 36, 256, 0, stream>>>(sysmb, xd, xp + 5 * HWP);
        conv_mid<6, 2><<<dim3(HWP / 64, 16), 64, 0, stream>>>(
            xp, pw1 + k * 32 * 6 * 9, pb1 + k * 32, pa1 + k, g1, HH, WW);
        conv_mid2<<<dim3(HWP / 128, 16), 64, 0, stream>>>(
            g1, pw2 + k * 32 * 32 * 9, pb2 + k * 32, pa2 + k, g2, HH, WW);
        conv3p_last<<<dim3(HWP / 64, 5), 64, 0, stream>>>(
            g2, pw3 + k * 5 * 32 * 9, pb3 + k * 5, xp, imgf, xp + 5 * HWP,
            (float*)d_out, k == NITER - 1 ? 1 : 0);
    }
}

// Round 14
// 1134.833 us; speedup vs baseline: 1.0914x; 1.0408x over previous
//
#include <hip/hip_runtime.h>

#define AA 60
#define HH 96
#define WW 96
#define DD 96
#define HWP (HH * WW)   // 9216
#define ADP (AA * DD)   // 5760
#define NITER 10
#define MATEL (60 * 96 * 9216)   // 53,084,160 elements per system matrix

typedef unsigned short ushort8 __attribute__((ext_vector_type(8)));
typedef float float4v __attribute__((ext_vector_type(4)));

__device__ inline float b2f(unsigned short u) {
    return __uint_as_float(((unsigned)u) << 16);
}
__device__ inline unsigned short f2b(float f) {
    unsigned u = __float_as_uint(f);
    u += 0x7FFFu + ((u >> 16) & 1u);
    return (unsigned short)(u >> 16);
}

// ---- f32 -> bf16 conversion of both system matrices (once per call) ----
// 64 B/thread per step: 4x float4 nontemporal loads -> 2x ushort8 stores.
__global__ __launch_bounds__(256) void cvt_kernel(const float* __restrict__ a,
                                                  const float* __restrict__ b,
                                                  ushort8* __restrict__ da,
                                                  ushort8* __restrict__ db, int n16) {
    int stride = gridDim.x * 256;
    for (int i = blockIdx.x * 256 + threadIdx.x; i < 2 * n16; i += stride) {
        const float* src; ushort8* dst; int j;
        if (i < n16) { src = a; dst = da; j = i; }
        else         { src = b; dst = db; j = i - n16; }
        const float4v* s = reinterpret_cast<const float4v*>(src) + 4 * (size_t)j;
        float4v x0 = __builtin_nontemporal_load(s);
        float4v x1 = __builtin_nontemporal_load(s + 1);
        float4v x2 = __builtin_nontemporal_load(s + 2);
        float4v x3 = __builtin_nontemporal_load(s + 3);
        ushort8 o0, o1;
        o0[0] = f2b(x0[0]); o0[1] = f2b(x0[1]); o0[2] = f2b(x0[2]); o0[3] = f2b(x0[3]);
        o0[4] = f2b(x1[0]); o0[5] = f2b(x1[1]); o0[6] = f2b(x1[2]); o0[7] = f2b(x1[3]);
        o1[0] = f2b(x2[0]); o1[1] = f2b(x2[1]); o1[2] = f2b(x2[2]); o1[3] = f2b(x2[3]);
        o1[4] = f2b(x3[0]); o1[5] = f2b(x3[1]); o1[6] = f2b(x3[2]); o1[7] = f2b(x3[3]);
        dst[2 * (size_t)j]     = o0;
        dst[2 * (size_t)j + 1] = o1;
    }
}

// xd[3][5760]: ch0=dual, ch1=evalop1, ch2=g ; xp[6][9216]: ch0..4=p2d, ch5=evalop2
__global__ __launch_bounds__(256) void init_kernel(const float* __restrict__ dual,
                            const float* __restrict__ g,
                            const float* __restrict__ primal,
                            float* __restrict__ xd, float* __restrict__ xp,
                            float* __restrict__ imgf, float* __restrict__ xp5) {
    int i = blockIdx.x * 256 + threadIdx.x;
    if (i < ADP) { xd[i] = dual[i]; xd[2 * ADP + i] = g[i]; }
    if (i < 5 * HWP) xp[i] = primal[i];
    if (i < HWP) {
        imgf[(i % WW) * HH + i / WW] = primal[HWP + i];
        xp5[i] = 0.f;
    }
}

// prod[row] = dot(norm_bf16[row,:9216], imgf); one wave per ROW-PAIR
__global__ __launch_bounds__(256) void einsum1_kernel(const unsigned short* __restrict__ norm,
                               const float* __restrict__ imgf,
                               float* __restrict__ out) {
    int rp   = blockIdx.x * 4 + (threadIdx.x >> 6);   // 0..2879
    int lane = threadIdx.x & 63;
    const unsigned short* r0 = norm + (size_t)(2 * rp) * HWP;
    const unsigned short* r1 = r0 + HWP;
    float s0 = 0.f, s1 = 0.f;
    for (int k = 0; k < HWP / 512; ++k) {   // 18 iters
        int n = 8 * lane + 512 * k;
        ushort8 a8 = *reinterpret_cast<const ushort8*>(r0 + n);
        ushort8 b8 = *reinterpret_cast<const ushort8*>(r1 + n);
        float4 i0 = *reinterpret_cast<const float4*>(imgf + n);
        float4 i1 = *reinterpret_cast<const float4*>(imgf + n + 4);
        s0 += b2f(a8[0]) * i0.x + b2f(a8[1]) * i0.y + b2f(a8[2]) * i0.z + b2f(a8[3]) * i0.w
            + b2f(a8[4]) * i1.x + b2f(a8[5]) * i1.y + b2f(a8[6]) * i1.z + b2f(a8[7]) * i1.w;
        s1 += b2f(b8[0]) * i0.x + b2f(b8[1]) * i0.y + b2f(b8[2]) * i0.z + b2f(b8[3]) * i0.w
            + b2f(b8[4]) * i1.x + b2f(b8[5]) * i1.y + b2f(b8[6]) * i1.z + b2f(b8[7]) * i1.w;
    }
#pragma unroll
    for (int off = 32; off > 0; off >>= 1) {
        s0 += __shfl_down(s0, off);
        s1 += __shfl_down(s1, off);
    }
    if (lane == 0) { out[2 * rp] = s0; out[2 * rp + 1] = s1; }
}

// vec[v] = sum_{a,n} sysm_bf16[a,v,n]*dual[a,n]; fortran-transposed scatter
__global__ __launch_bounds__(256) void einsum2_kernel(const unsigned short* __restrict__ sysm,
                               const float* __restrict__ xd,
                               float* __restrict__ xp5) {
    __shared__ float sd[4 * DD];
    int t  = threadIdx.x;
    int a0 = (blockIdx.x % 15) * 4;
    int v  = (blockIdx.x / 15) * 256 + t;
    for (int j = t; j < 4 * DD; j += 256) sd[j] = xd[a0 * DD + j];
    __syncthreads();
    float s = 0.f;
    for (int ai = 0; ai < 4; ++ai) {
        const unsigned short* row = sysm + ((size_t)(a0 + ai) * HWP + v) * DD;
        const float* dl = sd + ai * DD;
#pragma unroll
        for (int jj = 0; jj < DD / 8; ++jj) {
            ushort8 m8 = *reinterpret_cast<const ushort8*>(row + 8 * jj);
            s += b2f(m8[0]) * dl[8 * jj]     + b2f(m8[1]) * dl[8 * jj + 1]
               + b2f(m8[2]) * dl[8 * jj + 2] + b2f(m8[3]) * dl[8 * jj + 3]
               + b2f(m8[4]) * dl[8 * jj + 4] + b2f(m8[5]) * dl[8 * jj + 5]
               + b2f(m8[6]) * dl[8 * jj + 6] + b2f(m8[7]) * dl[8 * jj + 7];
        }
    }
    atomicAdd(xp5 + (v % HH) * WW + (v / HH), s);
}

// 3x3 conv pad=1, PReLU. Grid: (hw/64, Cout/NOUT), block 64.
template <int CIN, int NOUT>
__global__ __launch_bounds__(64) void conv_mid(
        const float* __restrict__ in,
        const float* __restrict__ wgt,   // [Cout][CIN][3][3]
        const float* __restrict__ bias,
        const float* __restrict__ alpha,
        float* __restrict__ out,
        int Hc, int Wc) {
    int hw  = Hc * Wc;
    int pix = blockIdx.x * 64 + threadIdx.x;
    int y = pix / Wc, x = pix % Wc;
    int oc0 = blockIdx.y * NOUT;
    const float* wb = wgt + (size_t)oc0 * CIN * 9;
    float a = alpha[0];
    float acc[NOUT];
#pragma unroll
    for (int o = 0; o < NOUT; ++o) acc[o] = bias[oc0 + o];
    for (int ci = 0; ci < CIN; ++ci) {
        const float* ip = in + ci * hw;
#pragma unroll
        for (int ky = 0; ky < 3; ++ky) {
            int yy = y + ky - 1;
            bool yok = (unsigned)yy < (unsigned)Hc;
#pragma unroll
            for (int kx = 0; kx < 3; ++kx) {
                int xx = x + kx - 1;
                bool vok = yok && ((unsigned)xx < (unsigned)Wc);
                float v = ip[vok ? yy * Wc + xx : 0];
                v = vok ? v : 0.f;
#pragma unroll
                for (int o = 0; o < NOUT; ++o)
                    acc[o] += wb[(o * CIN + ci) * 9 + ky * 3 + kx] * v;
            }
        }
    }
#pragma unroll
    for (int o = 0; o < NOUT; ++o) {
        float r = acc[o];
        r = (r >= 0.f) ? r : a * r;
        out[(oc0 + o) * hw + pix] = r;
    }
}

// dual conv3 (32->1) + residual into xd ch0, split over ci-chunks of 4 (atomicAdd)
__global__ __launch_bounds__(64) void conv3d_last(const float* __restrict__ in,
        const float* __restrict__ wgt,   // [32][9]
        const float* __restrict__ bias,  // [1]
        float* __restrict__ xd) {
    int pix = blockIdx.x * 64 + threadIdx.x;   // 0..5759
    int y = pix / DD, x = pix % DD;
    int c0 = blockIdx.y * 4;
    float r = (blockIdx.y == 0) ? bias[0] : 0.f;
    for (int ci = c0; ci < c0 + 4; ++ci) {
        const float* ip = in + ci * ADP;
#pragma unroll
        for (int ky = 0; ky < 3; ++ky) {
            int yy = y + ky - 1;
            bool yok = (unsigned)yy < (unsigned)AA;
#pragma unroll
            for (int kx = 0; kx < 3; ++kx) {
                int xx = x + kx - 1;
                bool vok = yok && ((unsigned)xx < (unsigned)DD);
                float v = ip[vok ? yy * DD + xx : 0];
                v = vok ? v : 0.f;
                r += wgt[ci * 9 + ky * 3 + kx] * v;
            }
        }
    }
    atomicAdd(xd + pix, r);
}

// primal conv3 (32->5) + residual into xp; fused: imgf for next iter (ch1),
// xp5 zero (ch2 block), final output write (ch0 block, last iter)
__global__ __launch_bounds__(64) void conv3p_last(const float* __restrict__ in,
        const float* __restrict__ wgt,   // [5][32][9]
        const float* __restrict__ bias,  // [5]
        float* __restrict__ xp, float* __restrict__ imgf,
        float* __restrict__ xp5, float* __restrict__ dout, int fin) {
    int pix = blockIdx.x * 64 + threadIdx.x;   // 0..9215
    int y = pix / WW, x = pix % WW;
    int oc = blockIdx.y;                       // 0..4
    const float* wb = wgt + (size_t)oc * 32 * 9;
    float r = bias[oc];
    for (int ci = 0; ci < 32; ++ci) {
        const float* ip = in + ci * HWP;
#pragma unroll
        for (int ky = 0; ky < 3; ++ky) {
            int yy = y + ky - 1;
            bool yok = (unsigned)yy < (unsigned)HH;
#pragma unroll
            for (int kx = 0; kx < 3; ++kx) {
                int xx = x + kx - 1;
                bool vok = yok && ((unsigned)xx < (unsigned)WW);
                float v = ip[vok ? yy * WW + xx : 0];
                v = vok ? v : 0.f;
                r += wb[ci * 9 + ky * 3 + kx] * v;
            }
        }
    }
    float nv = xp[oc * HWP + pix] + r;
    xp[oc * HWP + pix] = nv;
    if (oc == 1) imgf[x * HH + y] = nv;    // fortran flatten for next einsum1
    if (oc == 2) xp5[pix] = 0.f;           // clear evalop2 accumulator
    if (fin && oc == 0) dout[pix] = nv;    // final output
}

extern "C" void kernel_launch(void* const* d_in, const int* in_sizes, int n_in,
                              void* d_out, int out_size, void* d_ws, size_t ws_size,
                              hipStream_t stream) {
    const float* dual   = (const float*)d_in[0];
    const float* primal = (const float*)d_in[1];
    const float* g      = (const float*)d_in[2];
    const float* sysm   = (const float*)d_in[3];
    const float* norm   = (const float*)d_in[4];
    const float* dw1 = (const float*)d_in[5];
    const float* db1 = (const float*)d_in[6];
    const float* da1 = (const float*)d_in[7];
    const float* dw2 = (const float*)d_in[8];
    const float* db2 = (const float*)d_in[9];
    const float* da2 = (const float*)d_in[10];
    const float* dw3 = (const float*)d_in[11];
    const float* db3 = (const float*)d_in[12];
    const float* pw1 = (const float*)d_in[13];
    const float* pb1 = (const float*)d_in[14];
    const float* pa1 = (const float*)d_in[15];
    const float* pw2 = (const float*)d_in[16];
    const float* pb2 = (const float*)d_in[17];
    const float* pa2 = (const float*)d_in[18];
    const float* pw3 = (const float*)d_in[19];
    const float* pb3 = (const float*)d_in[20];

    unsigned short* normb = (unsigned short*)d_ws;     // MATEL bf16 [row][n]
    unsigned short* sysmb = normb + MATEL;             // MATEL bf16 [a][v][n]
    float* xd   = (float*)(sysmb + MATEL);             // 3*5760
    float* xp   = xd + 3 * ADP;                        // 6*9216
    float* imgf = xp + 6 * HWP;                        // 9216
    float* h1   = imgf + HWP;                          // 32*5760
    float* h2   = h1 + 32 * ADP;                       // 32*5760
    float* g1   = h2 + 32 * ADP;                       // 32*9216
    float* g2   = g1 + 32 * HWP;                       // 32*9216

    cvt_kernel<<<4096, 256, 0, stream>>>(norm, sysm, (ushort8*)normb, (ushort8*)sysmb, MATEL / 16);
    init_kernel<<<(5 * HWP + 255) / 256, 256, 0, stream>>>(dual, g, primal, xd, xp, imgf, xp + 5 * HWP);

    for (int k = 0; k < NITER; ++k) {
        // ---- dual half ----
        einsum1_kernel<<<ADP / 8, 256, 0, stream>>>(normb, imgf, xd + ADP);
        conv_mid<3, 2><<<dim3(ADP / 64, 16), 64, 0, stream>>>(
            xd, dw1 + k * 32 * 3 * 9, db1 + k * 32, da1 + k, h1, AA, DD);
        conv_mid<32, 2><<<dim3(ADP / 64, 16), 64, 0, stream>>>(
            h1, dw2 + k * 32 * 32 * 9, db2 + k * 32, da2 + k, h2, AA, DD);
        conv3d_last<<<dim3(ADP / 64, 8), 64, 0, stream>>>(
            h2, dw3 + k * 32 * 9, db3 + k, xd);
        // ---- primal half ----
        einsum2_kernel<<<15 * 36, 256, 0, stream>>>(sysmb, xd, xp + 5 * HWP);
        conv_mid<6, 2><<<dim3(HWP / 64, 16), 64, 0, stream>>>(
            xp, pw1 + k * 32 * 6 * 9, pb1 + k * 32, pa1 + k, g1, HH, WW);
        conv_mid<32, 2><<<dim3(HWP / 64, 16), 64, 0, stream>>>(
            g1, pw2 + k * 32 * 32 * 9, pb2 + k * 32, pa2 + k, g2, HH, WW);
        conv3p_last<<<dim3(HWP / 64, 5), 64, 0, stream>>>(
            g2, pw3 + k * 5 * 32 * 9, pb3 + k * 5, xp, imgf, xp + 5 * HWP,
            (float*)d_out, k == NITER - 1 ? 1 : 0);
    }
}

// Round 15
// 1093.394 us; speedup vs baseline: 1.1328x; 1.0379x over previous
//
#include <hip/hip_runtime.h>

#define AA 60
#define HH 96
#define WW 96
#define DD 96
#define HWP (HH * WW)   // 9216
#define ADP (AA * DD)   // 5760
#define NITER 10
#define MATEL (60 * 96 * 9216)   // 53,084,160 elements per system matrix

typedef unsigned short ushort8 __attribute__((ext_vector_type(8)));
typedef float float4v __attribute__((ext_vector_type(4)));

__device__ inline float b2f(unsigned short u) {
    return __uint_as_float(((unsigned)u) << 16);
}
__device__ inline unsigned short f2b(float f) {
    unsigned u = __float_as_uint(f);
    u += 0x7FFFu + ((u >> 16) & 1u);
    return (unsigned short)(u >> 16);
}

// ---- f32 -> bf16 conversion of both system matrices (once per call) ----
__global__ __launch_bounds__(256) void cvt_kernel(const float* __restrict__ a,
                                                  const float* __restrict__ b,
                                                  ushort8* __restrict__ da,
                                                  ushort8* __restrict__ db, int n8) {
    int stride = gridDim.x * 256;
    for (int i = blockIdx.x * 256 + threadIdx.x; i < 2 * n8; i += stride) {
        const float* src; ushort8* dst; int j;
        if (i < n8) { src = a; dst = da; j = i; }
        else        { src = b; dst = db; j = i - n8; }
        const float4v* s = reinterpret_cast<const float4v*>(src) + 2 * (size_t)j;
        float4v x = __builtin_nontemporal_load(s);
        float4v y = __builtin_nontemporal_load(s + 1);
        ushort8 o;
        o[0] = f2b(x[0]); o[1] = f2b(x[1]); o[2] = f2b(x[2]); o[3] = f2b(x[3]);
        o[4] = f2b(y[0]); o[5] = f2b(y[1]); o[6] = f2b(y[2]); o[7] = f2b(y[3]);
        dst[j] = o;
    }
}

// xd[3][5760]: ch0=dual, ch1=evalop1, ch2=g ; xp[6][9216]: ch0..4=p2d, ch5=evalop2
__global__ __launch_bounds__(256) void init_kernel(const float* __restrict__ dual,
                            const float* __restrict__ g,
                            const float* __restrict__ primal,
                            float* __restrict__ xd, float* __restrict__ xp,
                            float* __restrict__ imgf, float* __restrict__ xp5) {
    int i = blockIdx.x * 256 + threadIdx.x;
    if (i < ADP) { xd[i] = dual[i]; xd[2 * ADP + i] = g[i]; }
    if (i < 5 * HWP) xp[i] = primal[i];
    if (i < HWP) {
        imgf[(i % WW) * HH + i / WW] = primal[HWP + i];
        xp5[i] = 0.f;
    }
}

// prod[row] = dot(norm_bf16[row,:9216], imgf); one wave per ROW-PAIR
// (imgf loads shared across the two rows -> half the broadcast traffic)
__global__ __launch_bounds__(256) void einsum1_kernel(const unsigned short* __restrict__ norm,
                               const float* __restrict__ imgf,
                               float* __restrict__ out) {
    int rp   = blockIdx.x * 4 + (threadIdx.x >> 6);   // 0..2879
    int lane = threadIdx.x & 63;
    const unsigned short* r0 = norm + (size_t)(2 * rp) * HWP;
    const unsigned short* r1 = r0 + HWP;
    float s0 = 0.f, s1 = 0.f;
    for (int k = 0; k < HWP / 512; ++k) {   // 18 iters
        int n = 8 * lane + 512 * k;
        ushort8 a8 = *reinterpret_cast<const ushort8*>(r0 + n);
        ushort8 b8 = *reinterpret_cast<const ushort8*>(r1 + n);
        float4 i0 = *reinterpret_cast<const float4*>(imgf + n);
        float4 i1 = *reinterpret_cast<const float4*>(imgf + n + 4);
        s0 += b2f(a8[0]) * i0.x + b2f(a8[1]) * i0.y + b2f(a8[2]) * i0.z + b2f(a8[3]) * i0.w
            + b2f(a8[4]) * i1.x + b2f(a8[5]) * i1.y + b2f(a8[6]) * i1.z + b2f(a8[7]) * i1.w;
        s1 += b2f(b8[0]) * i0.x + b2f(b8[1]) * i0.y + b2f(b8[2]) * i0.z + b2f(b8[3]) * i0.w
            + b2f(b8[4]) * i1.x + b2f(b8[5]) * i1.y + b2f(b8[6]) * i1.z + b2f(b8[7]) * i1.w;
    }
#pragma unroll
    for (int off = 32; off > 0; off >>= 1) {
        s0 += __shfl_down(s0, off);
        s1 += __shfl_down(s1, off);
    }
    if (lane == 0) { out[2 * rp] = s0; out[2 * rp + 1] = s1; }
}

// vec[v] = sum_{a,n} sysm_bf16[a,v,n]*dual[a,n]; fortran-transposed scatter
__global__ __launch_bounds__(256) void einsum2_kernel(const unsigned short* __restrict__ sysm,
                               const float* __restrict__ xd,
                               float* __restrict__ xp5) {
    __shared__ float sd[4 * DD];
    int t  = threadIdx.x;
    int a0 = (blockIdx.x % 15) * 4;
    int v  = (blockIdx.x / 15) * 256 + t;
    for (int j = t; j < 4 * DD; j += 256) sd[j] = xd[a0 * DD + j];
    __syncthreads();
    float s = 0.f;
    for (int ai = 0; ai < 4; ++ai) {
        const unsigned short* row = sysm + ((size_t)(a0 + ai) * HWP + v) * DD;
        const float* dl = sd + ai * DD;
#pragma unroll
        for (int jj = 0; jj < DD / 8; ++jj) {
            ushort8 m8 = *reinterpret_cast<const ushort8*>(row + 8 * jj);
            s += b2f(m8[0]) * dl[8 * jj]     + b2f(m8[1]) * dl[8 * jj + 1]
               + b2f(m8[2]) * dl[8 * jj + 2] + b2f(m8[3]) * dl[8 * jj + 3]
               + b2f(m8[4]) * dl[8 * jj + 4] + b2f(m8[5]) * dl[8 * jj + 5]
               + b2f(m8[6]) * dl[8 * jj + 6] + b2f(m8[7]) * dl[8 * jj + 7];
        }
    }
    atomicAdd(xp5 + (v % HH) * WW + (v / HH), s);
}

// 3x3 conv pad=1, PReLU. Grid: (hw/64, Cout/NOUT), block 64.
template <int CIN, int NOUT>
__global__ __launch_bounds__(64) void conv_mid(
        const float* __restrict__ in,
        const float* __restrict__ wgt,   // [Cout][CIN][3][3]
        const float* __restrict__ bias,
        const float* __restrict__ alpha,
        float* __restrict__ out,
        int Hc, int Wc) {
    int hw  = Hc * Wc;
    int pix = blockIdx.x * 64 + threadIdx.x;
    int y = pix / Wc, x = pix % Wc;
    int oc0 = blockIdx.y * NOUT;
    const float* wb = wgt + (size_t)oc0 * CIN * 9;
    float a = alpha[0];
    float acc[NOUT];
#pragma unroll
    for (int o = 0; o < NOUT; ++o) acc[o] = bias[oc0 + o];
    for (int ci = 0; ci < CIN; ++ci) {
        const float* ip = in + ci * hw;
#pragma unroll
        for (int ky = 0; ky < 3; ++ky) {
            int yy = y + ky - 1;
            bool yok = (unsigned)yy < (unsigned)Hc;
#pragma unroll
            for (int kx = 0; kx < 3; ++kx) {
                int xx = x + kx - 1;
                bool vok = yok && ((unsigned)xx < (unsigned)Wc);
                float v = ip[vok ? yy * Wc + xx : 0];
                v = vok ? v : 0.f;
#pragma unroll
                for (int o = 0; o < NOUT; ++o)
                    acc[o] += wb[(o * CIN + ci) * 9 + ky * 3 + kx] * v;
            }
        }
    }
#pragma unroll
    for (int o = 0; o < NOUT; ++o) {
        float r = acc[o];
        r = (r >= 0.f) ? r : a * r;
        out[(oc0 + o) * hw + pix] = r;
    }
}

// dual conv3 (32->1) + residual into xd ch0, split over ci-chunks of 4 (atomicAdd)
__global__ __launch_bounds__(64) void conv3d_last(const float* __restrict__ in,
        const float* __restrict__ wgt,   // [32][9]
        const float* __restrict__ bias,  // [1]
        float* __restrict__ xd) {
    int pix = blockIdx.x * 64 + threadIdx.x;   // 0..5759
    int y = pix / DD, x = pix % DD;
    int c0 = blockIdx.y * 4;
    float r = (blockIdx.y == 0) ? bias[0] : 0.f;
    for (int ci = c0; ci < c0 + 4; ++ci) {
        const float* ip = in + ci * ADP;
#pragma unroll
        for (int ky = 0; ky < 3; ++ky) {
            int yy = y + ky - 1;
            bool yok = (unsigned)yy < (unsigned)AA;
#pragma unroll
            for (int kx = 0; kx < 3; ++kx) {
                int xx = x + kx - 1;
                bool vok = yok && ((unsigned)xx < (unsigned)DD);
                float v = ip[vok ? yy * DD + xx : 0];
                v = vok ? v : 0.f;
                r += wgt[ci * 9 + ky * 3 + kx] * v;
            }
        }
    }
    atomicAdd(xd + pix, r);
}

// primal conv3 (32->5) + residual into xp; fused: imgf for next iter (ch1),
// xp5 zero (ch2 block), final output write (ch0 block, last iter)
__global__ __launch_bounds__(64) void conv3p_last(const float* __restrict__ in,
        const float* __restrict__ wgt,   // [5][32][9]
        const float* __restrict__ bias,  // [5]
        float* __restrict__ xp, float* __restrict__ imgf,
        float* __restrict__ xp5, float* __restrict__ dout, int fin) {
    int pix = blockIdx.x * 64 + threadIdx.x;   // 0..9215
    int y = pix / WW, x = pix % WW;
    int oc = blockIdx.y;                       // 0..4
    const float* wb = wgt + (size_t)oc * 32 * 9;
    float r = bias[oc];
    for (int ci = 0; ci < 32; ++ci) {
        const float* ip = in + ci * HWP;
#pragma unroll
        for (int ky = 0; ky < 3; ++ky) {
            int yy = y + ky - 1;
            bool yok = (unsigned)yy < (unsigned)HH;
#pragma unroll
            for (int kx = 0; kx < 3; ++kx) {
                int xx = x + kx - 1;
                bool vok = yok && ((unsigned)xx < (unsigned)WW);
                float v = ip[vok ? yy * WW + xx : 0];
                v = vok ? v : 0.f;
                r += wb[ci * 9 + ky * 3 + kx] * v;
            }
        }
    }
    float nv = xp[oc * HWP + pix] + r;
    xp[oc * HWP + pix] = nv;
    if (oc == 1) imgf[x * HH + y] = nv;    // fortran flatten for next einsum1
    if (oc == 2) xp5[pix] = 0.f;           // clear evalop2 accumulator
    if (fin && oc == 0) dout[pix] = nv;    // final output
}

extern "C" void kernel_launch(void* const* d_in, const int* in_sizes, int n_in,
                              void* d_out, int out_size, void* d_ws, size_t ws_size,
                              hipStream_t stream) {
    const float* dual   = (const float*)d_in[0];
    const float* primal = (const float*)d_in[1];
    const float* g      = (const float*)d_in[2];
    const float* sysm   = (const float*)d_in[3];
    const float* norm   = (const float*)d_in[4];
    const float* dw1 = (const float*)d_in[5];
    const float* db1 = (const float*)d_in[6];
    const float* da1 = (const float*)d_in[7];
    const float* dw2 = (const float*)d_in[8];
    const float* db2 = (const float*)d_in[9];
    const float* da2 = (const float*)d_in[10];
    const float* dw3 = (const float*)d_in[11];
    const float* db3 = (const float*)d_in[12];
    const float* pw1 = (const float*)d_in[13];
    const float* pb1 = (const float*)d_in[14];
    const float* pa1 = (const float*)d_in[15];
    const float* pw2 = (const float*)d_in[16];
    const float* pb2 = (const float*)d_in[17];
    const float* pa2 = (const float*)d_in[18];
    const float* pw3 = (const float*)d_in[19];
    const float* pb3 = (const float*)d_in[20];

    unsigned short* normb = (unsigned short*)d_ws;     // MATEL bf16 [row][n]
    unsigned short* sysmb = normb + MATEL;             // MATEL bf16 [a][v][n]
    float* xd   = (float*)(sysmb + MATEL);             // 3*5760
    float* xp   = xd + 3 * ADP;                        // 6*9216
    float* imgf = xp + 6 * HWP;                        // 9216
    float* h1   = imgf + HWP;                          // 32*5760
    float* h2   = h1 + 32 * ADP;                       // 32*5760
    float* g1   = h2 + 32 * ADP;                       // 32*9216
    float* g2   = g1 + 32 * HWP;                       // 32*9216

    cvt_kernel<<<4096, 256, 0, stream>>>(norm, sysm, (ushort8*)normb, (ushort8*)sysmb, MATEL / 8);
    init_kernel<<<(5 * HWP + 255) / 256, 256, 0, stream>>>(dual, g, primal, xd, xp, imgf, xp + 5 * HWP);

    for (int k = 0; k < NITER; ++k) {
        // ---- dual half ----
        einsum1_kernel<<<ADP / 8, 256, 0, stream>>>(normb, imgf, xd + ADP);
        conv_mid<3, 2><<<dim3(ADP / 64, 16), 64, 0, stream>>>(
            xd, dw1 + k * 32 * 3 * 9, db1 + k * 32, da1 + k, h1, AA, DD);
        conv_mid<32, 2><<<dim3(ADP / 64, 16), 64, 0, stream>>>(
            h1, dw2 + k * 32 * 32 * 9, db2 + k * 32, da2 + k, h2, AA, DD);
        conv3d_last<<<dim3(ADP / 64, 8), 64, 0, stream>>>(
            h2, dw3 + k * 32 * 9, db3 + k, xd);
        // ---- primal half ----
        einsum2_kernel<<<15 * 36, 256, 0, stream>>>(sysmb, xd, xp + 5 * HWP);
        conv_mid<6, 2><<<dim3(HWP / 64, 16), 64, 0, stream>>>(
            xp, pw1 + k * 32 * 6 * 9, pb1 + k * 32, pa1 + k, g1, HH, WW);
        conv_mid<32, 2><<<dim3(HWP / 64, 16), 64, 0, stream>>>(
            g1, pw2 + k * 32 * 32 * 9, pb2 + k * 32, pa2 + k, g2, HH, WW);
        conv3p_last<<<dim3(HWP / 64, 5), 64, 0, stream>>>(
            g2, pw3 + k * 5 * 32 * 9, pb3 + k * 5, xp, imgf, xp + 5 * HWP,
            (float*)d_out, k == NITER - 1 ? 1 : 0);
    }
}